// Round 1
// baseline (80.685 us; speedup 1.0000x reference)
//
#include <hip/hip_runtime.h>

// Problem constants (from reference): B=4, N=256, FE=8, CIN=16, COUT=16, H=64
#define B_   4
#define N_   256
#define FE_  8
#define CIN_ 16
#define COUT_ 16
#define H_   64

// out[b,j,d] = sum_c node[b,j,c] * ( Wsum[b,j,c,d] + root[c,d] )
// Wsum[b,j]  = Hsum[b,j,:] @ W2 + N*b2        (reshaped [CIN,COUT])
// Hsum[b,j,h]= sum_i relu( edge[b,i,j,:] @ W1 + b1 )[h]
__global__ __launch_bounds__(256) void nnconv_fused_kernel(
    const float* __restrict__ node_attr,  // [B,N,CIN]
    const float* __restrict__ edge_adj,   // [B,N,N,FE]
    const float* __restrict__ W1,         // [FE,H]
    const float* __restrict__ b1,         // [H]
    const float* __restrict__ W2,         // [H, CIN*COUT]
    const float* __restrict__ b2,         // [CIN*COUT]
    const float* __restrict__ root,       // [CIN,COUT]
    float* __restrict__ out)              // [B,N,COUT]
{
    const int bj   = blockIdx.x;      // 0 .. B*N-1
    const int b    = bj >> 8;         // / N_
    const int j    = bj & (N_ - 1);
    const int t    = threadIdx.x;     // 0..255
    const int lane = t & 63;          // h index in step 1
    const int wave = t >> 6;          // 0..3

    __shared__ float e_s[N_][FE_];        // 8 KB: edge column j
    __shared__ float hpart[4][H_];        // per-wave partial Hsum
    __shared__ float Hsum[H_];
    __shared__ float contrib[CIN_][COUT_];

    // ---- stage edge column j: thread t loads the 8 floats of row i=t ----
    {
        const float4* src = (const float4*)(edge_adj +
            (((size_t)b * N_ + t) * N_ + j) * FE_);
        float4 a0 = src[0];
        float4 a1 = src[1];
        float4* dst = (float4*)(&e_s[t][0]);
        dst[0] = a0;
        dst[1] = a1;
    }

    // W1 column for h=lane into registers (redundant across waves, cheap)
    float w1r[FE_];
    #pragma unroll
    for (int f = 0; f < FE_; ++f) w1r[f] = W1[f * H_ + lane];
    const float b1r = b1[lane];

    __syncthreads();

    // ---- step 1: Hsum. wave g handles i = g, g+4, ... (each e_s word read once/block)
    float acc = 0.f;
    #pragma unroll 4
    for (int i = wave; i < N_; i += 4) {
        const float4* ev = (const float4*)(&e_s[i][0]);  // broadcast reads
        float4 e0 = ev[0];
        float4 e1 = ev[1];
        float v = b1r;
        v = fmaf(e0.x, w1r[0], v);
        v = fmaf(e0.y, w1r[1], v);
        v = fmaf(e0.z, w1r[2], v);
        v = fmaf(e0.w, w1r[3], v);
        v = fmaf(e1.x, w1r[4], v);
        v = fmaf(e1.y, w1r[5], v);
        v = fmaf(e1.z, w1r[6], v);
        v = fmaf(e1.w, w1r[7], v);
        acc += fmaxf(v, 0.f);
    }
    hpart[wave][lane] = acc;
    __syncthreads();

    if (t < H_) {
        Hsum[t] = hpart[0][t] + hpart[1][t] + hpart[2][t] + hpart[3][t];
    }
    __syncthreads();

    // ---- step 2: Wsum[t], t = c*COUT + d. W2 reads coalesced across lanes.
    float ws = (float)N_ * b2[t];
    #pragma unroll 8
    for (int h = 0; h < H_; ++h) {
        ws = fmaf(Hsum[h], W2[h * (CIN_ * COUT_) + t], ws);
    }

    // ---- step 3: out[d] = sum_c node[c] * (Wsum[c,d] + root[c,d])
    const int c = t >> 4;
    const int d = t & 15;
    const float nodec = node_attr[((size_t)b * N_ + j) * CIN_ + c];
    contrib[c][d] = nodec * (ws + root[t]);
    __syncthreads();

    if (t < COUT_) {
        float o = 0.f;
        #pragma unroll
        for (int cc = 0; cc < CIN_; ++cc) o += contrib[cc][t];
        out[((size_t)b * N_ + j) * COUT_ + t] = o;
    }
}

extern "C" void kernel_launch(void* const* d_in, const int* in_sizes, int n_in,
                              void* d_out, int out_size, void* d_ws, size_t ws_size,
                              hipStream_t stream) {
    const float* node_attr = (const float*)d_in[0];  // [B,N,CIN]
    const float* edge_adj  = (const float*)d_in[1];  // [B,N,N,FE]
    const float* W1        = (const float*)d_in[2];  // [FE,H]
    const float* b1        = (const float*)d_in[3];  // [H]
    const float* W2        = (const float*)d_in[4];  // [H,CIN*COUT]
    const float* b2        = (const float*)d_in[5];  // [CIN*COUT]
    const float* root      = (const float*)d_in[6];  // [CIN,COUT]
    float* out = (float*)d_out;                      // [B,N,COUT]

    dim3 grid(B_ * N_);
    dim3 block(256);
    nnconv_fused_kernel<<<grid, block, 0, stream>>>(
        node_attr, edge_adj, W1, b1, W2, b2, root, out);
}